// Round 3
// baseline (554.613 us; speedup 1.0000x reference)
//
#include <hip/hip_runtime.h>

#define BB 1024
#define TT 512
#define KK 64

// beta history: beta_t[j] = max_i(v_{t-1}[i] + T[i][j]) for t=1..511, stored
// PRE-emission and PRE-mask. 1024*511*64*4 B = 134 MB static device BSS.
__device__ float g_bhist[BB * (TT - 1) * KK];

// ---- wave(64)-wide reductions via butterfly shuffles (epilogues only) ----
__device__ __forceinline__ float wmaxf(float x) {
#pragma unroll
  for (int off = 32; off > 0; off >>= 1) x = fmaxf(x, __shfl_xor(x, off, 64));
  return x;
}
__device__ __forceinline__ float wsumf(float x) {
#pragma unroll
  for (int off = 32; off > 0; off >>= 1) x += __shfl_xor(x, off, 64);
  return x;
}
__device__ __forceinline__ int wsumi(int x) {
#pragma unroll
  for (int off = 32; off > 0; off >>= 1) x += __shfl_xor(x, off, 64);
  return x;
}

// readlane broadcast: lane i's value -> SGPR, usable as the 1 allowed scalar
// operand of v_fmac/v_add. VALU-pipe (per-SIMD), NOT the CU-shared LDS pipe.
__device__ __forceinline__ float bcast(float x, int l) {
  return __int_as_float(__builtin_amdgcn_readlane(__float_as_int(x), l));
}

// One block = one batch element. 128 threads = 2 waves:
//   wave0: forward algorithm (logZ) + gold score -> nll = logZ - gold
//   wave1: max-only viterbi recurrence (beta streamed to HBM) + equality
//          backtrace (ballot/ffs recovers argmax-first-index lazily).
// R3 rationale: R2's wall (1522 cyc/step) == 8 waves/CU x 16 broadcast
// ds_read_b128 x ~12 cyc = 1536 cyc of CU-shared LDS data path per step.
// LDS-bound, not VALU-bound (VALUBusy 64%). This round replaces the LDS
// broadcast with v_readlane -> SGPR -> v_fmac(s,v) : the all-lanes broadcast
// moves to the per-SIMD VALU pipe, per-step LDS traffic drops to one msk
// ds_read_b32. Arithmetic pairing/order identical to R2 (absmax 0.0).
extern "C" __global__ void __launch_bounds__(128, 2) crf_all_kernel(
    const float* __restrict__ em,      // [B,T,K]
    const int* __restrict__ tags,      // [B,T]
    const int* __restrict__ mask,      // [B,T]
    const float* __restrict__ trans,   // [K,K]
    const float* __restrict__ startt,  // [K]
    const float* __restrict__ endt,    // [K]
    float* __restrict__ out) {         // [B] nll ++ [B,T] path (as float)
  __shared__ float Tp[KK * KK];  // T'[j][i] at [j*64 + (i^j)] (XOR-swizzled)
  __shared__ int msk[TT];        // mask row, 2 KB

  const int b = blockIdx.x;
  const int lane = threadIdx.x & 63;
  const float* emb = em + (size_t)b * TT * KK;
  const int* maskb = mask + b * TT;
  const int* tagsb = tags + b * TT;

  // Stage mask row into LDS. Both waves write identical values (benign race,
  // aligned dwords); each wave's own writes are ordered before its reads.
#pragma unroll
  for (int u = 0; u < TT / KK; ++u) msk[u * KK + lane] = maskb[u * KK + lane];
  __builtin_amdgcn_wave_barrier();

  if (threadIdx.x < 64) {
    // ---------------- wave0: forward (logZ) + gold score ----------------
    float Ecol[KK];  // lane j holds column j of E = exp(trans)
#pragma unroll
    for (int i = 0; i < KK; ++i) Ecol[i] = __expf(trans[i * KK + lane]);

    float alpha = startt[lane] + emb[lane];

    auto fwd_step = [&](int t, float emv) {
      int m = msk[t];
      // Stabilization point: ANY in-range M works; readfirstlane (absmax 0.0
      // across all prior rounds with this).
      float M = __int_as_float(__builtin_amdgcn_readfirstlane(__float_as_int(alpha)));
      float p = __expf(alpha - M);  // lane i holds p_i
      float s0 = 0.f, s1 = 0.f, s2 = 0.f, s3 = 0.f;
#pragma unroll
      for (int i = 0; i < KK; i += 4) {  // same pairing/order as R2
        s0 = fmaf(bcast(p, i + 0), Ecol[i + 0], s0);
        s1 = fmaf(bcast(p, i + 1), Ecol[i + 1], s1);
        s2 = fmaf(bcast(p, i + 2), Ecol[i + 2], s2);
        s3 = fmaf(bcast(p, i + 3), Ecol[i + 3], s3);
      }
      float na = __logf((s0 + s1) + (s2 + s3)) + M + emv;
      alpha = (m != 0) ? na : alpha;
    };

    // depth-8 register prefetch ring over t
    float er[8];
#pragma unroll
    for (int k = 0; k < 8; ++k) er[k] = emb[(size_t)(1 + k) * KK + lane];
    for (int tb = 1; tb <= TT - 15; tb += 8) {  // t = 1 .. 504
#pragma unroll
      for (int k = 0; k < 8; ++k) {
        int t = tb + k;
        float emv = er[k];
        int tp = t + 8;
        tp = (tp < TT) ? tp : (TT - 1);  // clamped (redundant loads harmless)
        er[k] = emb[(size_t)tp * KK + lane];
        fwd_step(t, emv);
      }
    }
#pragma unroll
    for (int k = 0; k < 7; ++k) {  // t = 505 .. 511, ring slots 0..6
      fwd_step(TT - 7 + k, er[k]);
    }

    // logZ = logsumexp(alpha + end) — exact max (runs once)
    float x = alpha + endt[lane];
    float M2 = wmaxf(x);
    float S = wsumf(__expf(x - M2));
    float logZ = __logf(S) + M2;

    // gold score: lane j covers t = u*64 + j
    float acc = 0.f;
    int msum = 0;
#pragma unroll
    for (int u = 0; u < TT / KK; ++u) {
      int t2 = u * KK + lane;
      int tg = tagsb[t2];
      int m = msk[t2];
      msum += m;
      float mf = (float)m;
      acc = fmaf(emb[(size_t)t2 * KK + tg], mf, acc);
      if (t2 >= 1) acc = fmaf(trans[tagsb[t2 - 1] * KK + tg], mf, acc);
    }
    acc = wsumf(acc);
    msum = wsumi(msum);
    if (lane == 0) {
      float gold = acc + startt[tagsb[0]] + endt[tagsb[msum - 1]];
      out[b] = logZ - gold;
    }
  } else {
    // ---------------- wave1: max-only viterbi + equality backtrace --------
    float Tcol[KK];  // lane j holds column j of trans
#pragma unroll
    for (int i = 0; i < KK; ++i) Tcol[i] = trans[i * KK + lane];
    // Populate swizzled T': lane j writes Tp[j*64 + (i^j)] = trans[i][j].
    // At each unrolled i, bank = (i^j)%32 over j=0..63 hits every bank
    // exactly twice (2-way aliasing is free) -> ~0 conflicts (was 917K).
#pragma unroll
    for (int i = 0; i < KK; ++i) Tp[lane * KK + (i ^ lane)] = Tcol[i];
    __builtin_amdgcn_wave_barrier();

    float* bh = g_bhist + (size_t)b * (TT - 1) * KK;
    float v = startt[lane] + emb[lane];

    auto vit_step = [&](int t, float emv) {
      int m = msk[t];
      // Max-only: 4 accumulators; fmaxf(acc, fmaxf(a,b)) fuses to v_max3.
      // Max value is order-independent (exact); equality backtrace matches
      // bitwise because fmax returns one operand exactly.
      float m0 = -3.402823466e38f, m1 = m0, m2 = m0, m3 = m0;
#pragma unroll
      for (int i = 0; i < KK; i += 8) {
        float a0 = bcast(v, i + 0) + Tcol[i + 0];
        float a1 = bcast(v, i + 1) + Tcol[i + 1];
        float a2 = bcast(v, i + 2) + Tcol[i + 2];
        float a3 = bcast(v, i + 3) + Tcol[i + 3];
        float a4 = bcast(v, i + 4) + Tcol[i + 4];
        float a5 = bcast(v, i + 5) + Tcol[i + 5];
        float a6 = bcast(v, i + 6) + Tcol[i + 6];
        float a7 = bcast(v, i + 7) + Tcol[i + 7];
        m0 = fmaxf(m0, fmaxf(a0, a1));
        m1 = fmaxf(m1, fmaxf(a2, a3));
        m2 = fmaxf(m2, fmaxf(a4, a5));
        m3 = fmaxf(m3, fmaxf(a6, a7));
      }
      float best = fmaxf(fmaxf(m0, m1), fmaxf(m2, m3));
      bh[(size_t)(t - 1) * KK + lane] = best;  // coalesced 256B/step stream-out
      v = (m != 0) ? (best + emv) : v;
    };

    // depth-8 register prefetch ring over t
    float er[8];
#pragma unroll
    for (int k = 0; k < 8; ++k) er[k] = emb[(size_t)(1 + k) * KK + lane];
    for (int tb = 1; tb <= TT - 15; tb += 8) {  // t = 1 .. 504
#pragma unroll
      for (int k = 0; k < 8; ++k) {
        int t = tb + k;
        float emv = er[k];
        int tp = t + 8;
        tp = (tp < TT) ? tp : (TT - 1);
        er[k] = emb[(size_t)tp * KK + lane];
        vit_step(t, emv);
      }
    }
#pragma unroll
    for (int k = 0; k < 7; ++k) {  // t = 505 .. 511
      vit_step(TT - 7 + k, er[k]);
    }

    // last = argmax(v + end), first-index on exact ties (runs once)
    float sc = v + endt[lane];
    int idx = lane;
#pragma unroll
    for (int off = 32; off > 0; off >>= 1) {
      float osc = __shfl_xor(sc, off, 64);
      int oidx = __shfl_xor(idx, off, 64);
      if (osc > sc || (osc == sc && oidx < idx)) { sc = osc; idx = oidx; }
    }
    // ---- equality backtrace ----
    // Step tt (tag known): scalar beta_tt[tag] = bh[tt-1][tag] via shfl;
    // vector v_{tt-1}[i] = bh[tt-2][i] + em[tt-1][i] (bitwise == forward's v,
    // same operands & add order). score[i] = v[i] + T'[tag][i]; first lane
    // with score==beta is np.argmax. History rows are tag-independent ->
    // chunk-prefetch 8 steps.
    int tag = idx;
    float* pout = out + BB + (size_t)b * TT;
    int tt = TT - 1;
    while (tt >= 9) {  // process tt .. tt-7
      float Brow[9], Erow[8];
      int Mrow[8];
#pragma unroll
      for (int k = 0; k < 9; ++k) Brow[k] = bh[(size_t)(tt - 1 - k) * KK + lane];
#pragma unroll
      for (int k = 0; k < 8; ++k) Erow[k] = emb[(size_t)(tt - 1 - k) * KK + lane];
#pragma unroll
      for (int k = 0; k < 8; ++k) Mrow[k] = msk[tt - k];
#pragma unroll
      for (int k = 0; k < 8; ++k) {
        if (lane == 0) pout[tt - k] = (float)tag;
        float beta = __shfl(Brow[k], tag, 64);
        float sc2 = (Brow[k + 1] + Erow[k]) + Tp[tag * KK + (lane ^ tag)];
        unsigned long long mm = __ballot(sc2 == beta);
        int nt = (int)__ffsll(mm) - 1;
        tag = (Mrow[k] != 0) ? nt : tag;
      }
      tt -= 8;
    }
    for (; tt >= 2; --tt) {
      if (lane == 0) pout[tt] = (float)tag;
      float beta = __shfl(bh[(size_t)(tt - 1) * KK + lane], tag, 64);
      float sc2 = (bh[(size_t)(tt - 2) * KK + lane] + emb[(size_t)(tt - 1) * KK + lane]) +
                  Tp[tag * KK + (lane ^ tag)];
      unsigned long long mm = __ballot(sc2 == beta);
      int nt = (int)__ffsll(mm) - 1;
      tag = (msk[tt] != 0) ? nt : tag;
    }
    {  // tt == 1: vector row is v_0 = start + em[0] (bitwise == forward init)
      if (lane == 0) pout[1] = (float)tag;
      float beta = __shfl(bh[lane], tag, 64);
      float sc2 = (startt[lane] + emb[lane]) + Tp[tag * KK + (lane ^ tag)];
      unsigned long long mm = __ballot(sc2 == beta);
      int nt = (int)__ffsll(mm) - 1;
      tag = (msk[1] != 0) ? nt : tag;
      if (lane == 0) pout[0] = (float)tag;
    }
  }
}

extern "C" void kernel_launch(void* const* d_in, const int* in_sizes, int n_in,
                              void* d_out, int out_size, void* d_ws, size_t ws_size,
                              hipStream_t stream) {
  (void)in_sizes; (void)n_in; (void)out_size; (void)d_ws; (void)ws_size;
  const float* em = (const float*)d_in[0];
  const int* tags = (const int*)d_in[1];
  const int* mask = (const int*)d_in[2];
  const float* trans = (const float*)d_in[3];
  const float* startt = (const float*)d_in[4];
  const float* endt = (const float*)d_in[5];
  float* out = (float*)d_out;
  crf_all_kernel<<<dim3(BB), dim3(128), 0, stream>>>(em, tags, mask, trans,
                                                     startt, endt, out);
}